// Round 2
// baseline (834.346 us; speedup 1.0000x reference)
//
#include <hip/hip_runtime.h>

// Problem constants (B=2, S=4096, D=2048, H=16, KVH=4, HD=128)
#define S_LEN 4096
#define BATCH 2
#define NH 16
#define NKVH 4
#define HD_DIM 128
#define DMODEL 2048
#define MROWS (BATCH * S_LEN)          // 8192
#define KVDIM (NKVH * HD_DIM)          // 512
#define QSCALE 0.08838834764831845f    // 1/sqrt(128)

typedef __attribute__((ext_vector_type(8))) short bf16x8;
typedef __attribute__((ext_vector_type(4))) float f32x4;

__device__ __forceinline__ unsigned short f2bf(float f) {
    unsigned int u = __float_as_uint(f);
    u += 0x7FFFu + ((u >> 16) & 1u);   // round-to-nearest-even
    return (unsigned short)(u >> 16);
}
__device__ __forceinline__ float bf2f(unsigned short h) {
    return __uint_as_float(((unsigned int)h) << 16);
}

// async global->LDS, 16B per lane; dest = uniform base + lane*16
__device__ __forceinline__ void gload_lds16(const void* g, void* lds) {
    __builtin_amdgcn_global_load_lds(
        (const __attribute__((address_space(1))) void*)g,
        (__attribute__((address_space(3))) void*)lds, 16, 0, 0);
}

// XOR swizzles (involutions on 16B slots), one per LDS row pitch.
// swz64 : 64B rows  ([R][32] bf16)  — XOR row bits 0-1 into granule bits 0-1
// swz128: 128B rows ([R][64] bf16)  — XOR row bits 0-2 into granule bits 0-2
// swzK  : 256B rows ([R][128] bf16) — XOR row bits 0-2 into granule bits 0-2
// Each makes every consecutive-8-lane phase of a b128 fragment read hit 8
// distinct 16B granules (conflict-free under the 32-bank/128B wrap).
__device__ __forceinline__ unsigned swz64 (unsigned off) { return off ^ (((off >> 7) & 3u) << 4); }
__device__ __forceinline__ unsigned swz128(unsigned off) { return off ^ (((off >> 7) & 7u) << 4); }
__device__ __forceinline__ unsigned swzK  (unsigned off) { return off ^ (((off >> 8) & 7u) << 4); }

// ---------------- cast x (fp32 -> bf16), vectorized ----------------
__global__ __launch_bounds__(256) void cast_f32_bf16(
    const float* __restrict__ in, unsigned short* __restrict__ out, int n4) {
    int i = blockIdx.x * blockDim.x + threadIdx.x;
    if (i >= n4) return;
    const float4 v = ((const float4*)in)[i];
    ushort4 o;
    o.x = f2bf(v.x); o.y = f2bf(v.y); o.z = f2bf(v.z); o.w = f2bf(v.w);
    ((ushort4*)out)[i] = o;
}

// ------------- transpose-cast weights: W[K][N] f32 -> Wt[N][K] bf16 -------------
__global__ __launch_bounds__(256) void transpose_cast(
    const float* __restrict__ W, unsigned short* __restrict__ Wt, int K, int N) {
    __shared__ float tile[64][65];
    const int bk = blockIdx.x, bn = blockIdx.y;
    const int t = threadIdx.x;
#pragma unroll
    for (int rep = 0; rep < 16; ++rep) {
        int idx = rep * 256 + t;
        int r = idx >> 6, c = idx & 63;
        tile[r][c] = W[(size_t)(bk * 64 + r) * N + bn * 64 + c];
    }
    __syncthreads();
#pragma unroll
    for (int rep = 0; rep < 16; ++rep) {
        int idx = rep * 256 + t;
        int r = idx >> 6, c = idx & 63;   // r = n-local, c = k-local
        Wt[(size_t)(bn * 64 + r) * K + bk * 64 + c] = f2bf(tile[c][r]);
    }
}

// ------------- RoPE in-place on bf16 [MROWS][nh*128]; scale folded in -------------
__global__ __launch_bounds__(256) void rope_kernel(
    unsigned short* __restrict__ q, const float* __restrict__ cosb,
    const float* __restrict__ sinb, int nh, float scale) {
    int gid = blockIdx.x * blockDim.x + threadIdx.x;
    int d = gid & 63;
    int h = (gid >> 6) % nh;
    int m = gid / (64 * nh);
    if (m >= MROWS) return;
    size_t base = (size_t)m * (nh * 128) + h * 128;
    float x1 = bf2f(q[base + d]);
    float x2 = bf2f(q[base + d + 64]);
    float c1 = cosb[m * 128 + d],  c2 = cosb[m * 128 + d + 64];
    float s1 = sinb[m * 128 + d],  s2 = sinb[m * 128 + d + 64];
    q[base + d]      = f2bf((x1 * c1 - x2 * s1) * scale);
    q[base + d + 64] = f2bf((x2 * c2 + x1 * s2) * scale);
}

// ------------- V transpose: vb[MROWS][512] -> vt[B][KVH][128][S] -------------
__global__ __launch_bounds__(256) void transpose_v(
    const unsigned short* __restrict__ V, unsigned short* __restrict__ Vt) {
    __shared__ unsigned short tile[64][65];
    const int st = blockIdx.x, dt = blockIdx.y, bk = blockIdx.z;
    const int b = bk / NKVH, kvh = bk % NKVH;
    const int t = threadIdx.x;
#pragma unroll
    for (int rep = 0; rep < 16; ++rep) {
        int idx = rep * 256 + t;
        int r = idx >> 6, c = idx & 63;  // r = s-local, c = d-local
        tile[r][c] = V[(size_t)(b * S_LEN + st * 64 + r) * KVDIM + kvh * HD_DIM + dt * 64 + c];
    }
    __syncthreads();
#pragma unroll
    for (int rep = 0; rep < 16; ++rep) {
        int idx = rep * 256 + t;
        int r = idx >> 6, c = idx & 63;  // r = d-local, c = s-local
        Vt[((size_t)(b * NKVH + kvh) * HD_DIM + dt * 64 + r) * S_LEN + st * 64 + c] = tile[c][r];
    }
}

// ------------- bf16 GEMM: C[M][N] = A[M][K] * Bt[N][K]^T -------------
// 128x128 tile, BK=32, 4 waves (2x2 of 64x64). m97-style global_load_lds staging
// with pre-swizzled source so LDS reads are conflict-free.
template <bool OUT_F32>
__global__ __launch_bounds__(256) void gemm_bt(
    const unsigned short* __restrict__ A, const unsigned short* __restrict__ Bt,
    void* __restrict__ Cout, int M, int N, int K) {
    __shared__ unsigned short As[128 * 32];
    __shared__ unsigned short Bs[128 * 32];
    const int nbn = N >> 7;
    const int bm = blockIdx.x / nbn, bn = blockIdx.x % nbn;
    const int tid = threadIdx.x;
    const int w = tid >> 6, l = tid & 63;
    const int wm = w >> 1, wn = w & 1;
    const int lr = l & 15, lg = l >> 4;
    const unsigned m0 = bm << 7, n0 = bn << 7;

    f32x4 acc[4][4];
#pragma unroll
    for (int i = 0; i < 4; ++i)
#pragma unroll
        for (int j = 0; j < 4; ++j) acc[i][j] = (f32x4){0.f, 0.f, 0.f, 0.f};

    for (int k0 = 0; k0 < K; k0 += 32) {
        __syncthreads();
#pragma unroll
        for (int c = 0; c < 2; ++c) {
            unsigned ch = w * 2 + c;
            unsigned L = ch * 1024u + (unsigned)l * 16u;
            unsigned f = swz64(L);
            unsigned row = f >> 6, colb = f & 63u;
            const char* gA = (const char*)(A + (size_t)(m0 + row) * K + k0) + colb;
            gload_lds16(gA, (char*)As + ch * 1024u);
            const char* gB = (const char*)(Bt + (size_t)(n0 + row) * K + k0) + colb;
            gload_lds16(gB, (char*)Bs + ch * 1024u);
        }
        __syncthreads();
        bf16x8 af[4], bfr[4];
#pragma unroll
        for (int mf = 0; mf < 4; ++mf) {
            unsigned row = wm * 64 + mf * 16 + lr;
            af[mf] = *(const bf16x8*)((const char*)As + swz64(row * 64u + lg * 16u));
        }
#pragma unroll
        for (int nf = 0; nf < 4; ++nf) {
            unsigned row = wn * 64 + nf * 16 + lr;
            bfr[nf] = *(const bf16x8*)((const char*)Bs + swz64(row * 64u + lg * 16u));
        }
#pragma unroll
        for (int mf = 0; mf < 4; ++mf)
#pragma unroll
            for (int nf = 0; nf < 4; ++nf)
                acc[mf][nf] = __builtin_amdgcn_mfma_f32_16x16x32_bf16(
                    af[mf], bfr[nf], acc[mf][nf], 0, 0, 0);
    }
#pragma unroll
    for (int mf = 0; mf < 4; ++mf)
#pragma unroll
        for (int nf = 0; nf < 4; ++nf)
#pragma unroll
            for (int r = 0; r < 4; ++r) {
                unsigned row = m0 + wm * 64 + mf * 16 + lg * 4 + r;
                unsigned col = n0 + wn * 64 + nf * 16 + lr;
                float v = acc[mf][nf][r];
                if (OUT_F32) ((float*)Cout)[(size_t)row * N + col] = v;
                else ((unsigned short*)Cout)[(size_t)row * N + col] = f2bf(v);
            }
}

// ------------- causal GQA flash attention, KVBLK = 64 -------------
// Block = 4 waves, 64 q-rows (16/wave). Q scale pre-folded into Qb.
// Qb [MROWS][2048] bf16 (RoPE'd, scaled), Kb [MROWS][512] bf16 (RoPE'd),
// Vt [B][KVH][128][S] bf16. O [MROWS][2048] bf16.
__global__ __launch_bounds__(256) void attn_fwd(
    const unsigned short* __restrict__ Qb, const unsigned short* __restrict__ Kb,
    const unsigned short* __restrict__ Vt, unsigned short* __restrict__ O) {
    __shared__ unsigned short Ks[64 * 128];    // 16 KB, 256B rows, swzK
    __shared__ unsigned short Vs[128 * 64];    // 16 KB, 128B rows, swz128
    __shared__ unsigned short Ps[4][16 * 72];  // per-wave P (16 q x 64 kv), pitch 144B

    const int nqt = S_LEN / 64;                      // 64
    const int bh = blockIdx.x & (BATCH * NH - 1);    // 32 heads per q-tile
    const int qt = (nqt - 1) - (blockIdx.x >> 5);    // heavy tiles first
    const int b = bh >> 4, h = bh & 15;
    const int kvh = h >> 2;

    const int tid = threadIdx.x;
    const int w = tid >> 6, l = tid & 63;
    const int lr = l & 15, lg = l >> 4;
    const int sq_base = qt * 64 + w * 16;

    bf16x8 qf[4];
    {
        const unsigned short* qrow = Qb + (size_t)(b * S_LEN + sq_base + lr) * DMODEL + h * HD_DIM;
#pragma unroll
        for (int kk = 0; kk < 4; ++kk)
            qf[kk] = *(const bf16x8*)(qrow + kk * 32 + lg * 8);
    }

    float mrun[4], lrun[4];
#pragma unroll
    for (int r = 0; r < 4; ++r) { mrun[r] = -INFINITY; lrun[r] = 0.f; }
    f32x4 acc[8];
#pragma unroll
    for (int d = 0; d < 8; ++d) acc[d] = (f32x4){0.f, 0.f, 0.f, 0.f};

    const int nt = qt + 1;
    for (int t = 0; t < nt; ++t) {
        const int kv0 = t * 64;
        __syncthreads();
#pragma unroll
        for (int c = 0; c < 4; ++c) {
            unsigned ch = w * 4 + c;
            unsigned L = ch * 1024u + (unsigned)l * 16u;
            {   // K tile [64][128]
                unsigned f = swzK(L);
                unsigned r_ = f >> 8, cb = f & 255u;
                const char* g = (const char*)(Kb + (size_t)(b * S_LEN + kv0 + r_) * KVDIM + kvh * HD_DIM) + cb;
                gload_lds16(g, (char*)Ks + ch * 1024u);
            }
            {   // V^T tile [128][64]
                unsigned f = swz128(L);
                unsigned d = f >> 7, cb = f & 127u;
                const char* g = (const char*)(Vt + ((size_t)(b * NKVH + kvh) * HD_DIM + d) * S_LEN + kv0) + cb;
                gload_lds16(g, (char*)Vs + ch * 1024u);
            }
        }
        __syncthreads();

        // ---- QK^T: S[16q][64kv] per wave ----
        f32x4 sc[4];
#pragma unroll
        for (int nf = 0; nf < 4; ++nf) sc[nf] = (f32x4){0.f, 0.f, 0.f, 0.f};
#pragma unroll
        for (int kk = 0; kk < 4; ++kk)
#pragma unroll
            for (int nf = 0; nf < 4; ++nf) {
                unsigned row = nf * 16 + lr;
                bf16x8 kfr = *(const bf16x8*)((const char*)Ks + swzK(row * 256u + kk * 64u + lg * 16u));
                sc[nf] = __builtin_amdgcn_mfma_f32_16x16x32_bf16(qf[kk], kfr, sc[nf], 0, 0, 0);
            }

        // ---- online softmax (rows r = lg*4+0..3 of this wave's 16) ----
#pragma unroll
        for (int r = 0; r < 4; ++r) {
            int q_abs = sq_base + lg * 4 + r;
            float s0 = sc[0][r]; if (kv0 + lr > q_abs)      s0 = -INFINITY;
            float s1 = sc[1][r]; if (kv0 + 16 + lr > q_abs) s1 = -INFINITY;
            float s2 = sc[2][r]; if (kv0 + 32 + lr > q_abs) s2 = -INFINITY;
            float s3 = sc[3][r]; if (kv0 + 48 + lr > q_abs) s3 = -INFINITY;
            float tm = fmaxf(fmaxf(s0, s1), fmaxf(s2, s3));
            tm = fmaxf(tm, __shfl_xor(tm, 1, 16));
            tm = fmaxf(tm, __shfl_xor(tm, 2, 16));
            tm = fmaxf(tm, __shfl_xor(tm, 4, 16));
            tm = fmaxf(tm, __shfl_xor(tm, 8, 16));
            float mnew = fmaxf(mrun[r], tm);
            float corr = __expf(mrun[r] - mnew);
            float p0 = __expf(s0 - mnew);
            float p1 = __expf(s1 - mnew);
            float p2 = __expf(s2 - mnew);
            float p3 = __expf(s3 - mnew);
            float rs = (p0 + p1) + (p2 + p3);
            rs += __shfl_xor(rs, 1, 16);
            rs += __shfl_xor(rs, 2, 16);
            rs += __shfl_xor(rs, 4, 16);
            rs += __shfl_xor(rs, 8, 16);
            lrun[r] = corr * lrun[r] + rs;
            mrun[r] = mnew;
#pragma unroll
            for (int d = 0; d < 8; ++d) acc[d][r] *= corr;
            int prow = (lg * 4 + r) * 72;
            Ps[w][prow + lr]      = f2bf(p0);
            Ps[w][prow + 16 + lr] = f2bf(p1);
            Ps[w][prow + 32 + lr] = f2bf(p2);
            Ps[w][prow + 48 + lr] = f2bf(p3);
        }

        // ---- PV: O[16q][128d] += P[16q][64kv] * V[64kv][128d] ----
        bf16x8 pf[2];
#pragma unroll
        for (int ks = 0; ks < 2; ++ks)
            pf[ks] = *(const bf16x8*)(&Ps[w][lr * 72 + ks * 32 + lg * 8]);
#pragma unroll
        for (int d = 0; d < 8; ++d)
#pragma unroll
            for (int ks = 0; ks < 2; ++ks) {
                unsigned row = d * 16 + lr;
                bf16x8 vf = *(const bf16x8*)((const char*)Vs + swz128(row * 128u + ks * 64u + lg * 16u));
                acc[d] = __builtin_amdgcn_mfma_f32_16x16x32_bf16(pf[ks], vf, acc[d], 0, 0, 0);
            }
    }

    float inv[4];
#pragma unroll
    for (int r = 0; r < 4; ++r) inv[r] = 1.f / lrun[r];
#pragma unroll
    for (int d = 0; d < 8; ++d)
#pragma unroll
        for (int r = 0; r < 4; ++r) {
            size_t row = (size_t)(b * S_LEN + sq_base + lg * 4 + r);
            O[row * DMODEL + h * HD_DIM + d * 16 + lr] = f2bf(acc[d][r] * inv[r]);
        }
}

extern "C" void kernel_launch(void* const* d_in, const int* in_sizes, int n_in,
                              void* d_out, int out_size, void* d_ws, size_t ws_size,
                              hipStream_t stream) {
    (void)in_sizes; (void)n_in; (void)out_size; (void)ws_size;
    const float* x    = (const float*)d_in[0];
    const float* cosb = (const float*)d_in[1];
    const float* sinb = (const float*)d_in[2];
    const float* wq   = (const float*)d_in[3];
    const float* wk   = (const float*)d_in[4];
    const float* wv   = (const float*)d_in[5];
    const float* wo   = (const float*)d_in[6];
    float* out = (float*)d_out;

    char* ws = (char*)d_ws;
    const size_t MB = 1ull << 20;
    unsigned short* xb  = (unsigned short*)(ws + 0);        // 32MB (x bf16; dead after V GEMM)
    unsigned short* aob = (unsigned short*)(ws + 0);        // 32MB (attn out; reuses xb)
    unsigned short* wqt = (unsigned short*)(ws + 32 * MB);  // 8MB
    unsigned short* wkt = (unsigned short*)(ws + 40 * MB);  // 2MB
    unsigned short* wvt = (unsigned short*)(ws + 42 * MB);  // 2MB
    unsigned short* wot = (unsigned short*)(ws + 44 * MB);  // 8MB
    unsigned short* qb  = (unsigned short*)(ws + 52 * MB);  // 32MB
    unsigned short* kb  = (unsigned short*)(ws + 84 * MB);  // 8MB
    unsigned short* vb  = (unsigned short*)(ws + 92 * MB);  // 8MB
    unsigned short* vtb = (unsigned short*)(ws + 100 * MB); // 8MB  (total 108MB)

    cast_f32_bf16<<<16384, 256, 0, stream>>>(x, xb, (MROWS * DMODEL) / 4);
    transpose_cast<<<dim3(32, 32), 256, 0, stream>>>(wq, wqt, DMODEL, DMODEL);
    transpose_cast<<<dim3(32, 8),  256, 0, stream>>>(wk, wkt, DMODEL, KVDIM);
    transpose_cast<<<dim3(32, 8),  256, 0, stream>>>(wv, wvt, DMODEL, KVDIM);
    transpose_cast<<<dim3(32, 32), 256, 0, stream>>>(wo, wot, DMODEL, DMODEL);

    gemm_bt<false><<<1024, 256, 0, stream>>>(xb, wqt, qb, MROWS, DMODEL, DMODEL);
    gemm_bt<false><<<256,  256, 0, stream>>>(xb, wkt, kb, MROWS, KVDIM, DMODEL);
    gemm_bt<false><<<256,  256, 0, stream>>>(xb, wvt, vb, MROWS, KVDIM, DMODEL);

    rope_kernel<<<(MROWS * NH * 64) / 256,   256, 0, stream>>>(qb, cosb, sinb, NH, QSCALE);
    rope_kernel<<<(MROWS * NKVH * 64) / 256, 256, 0, stream>>>(kb, cosb, sinb, NKVH, 1.0f);
    transpose_v<<<dim3(64, 2, 8), 256, 0, stream>>>(vb, vtb);

    attn_fwd<<<2048, 256, 0, stream>>>(qb, kb, vtb, aob);

    gemm_bt<true><<<1024, 256, 0, stream>>>(aob, wot, out, MROWS, DMODEL, DMODEL);
}

// Round 3
// 798.503 us; speedup vs baseline: 1.0449x; 1.0449x over previous
//
#include <hip/hip_runtime.h>

// Problem constants (B=2, S=4096, D=2048, H=16, KVH=4, HD=128)
#define S_LEN 4096
#define BATCH 2
#define NH 16
#define NKVH 4
#define HD_DIM 128
#define DMODEL 2048
#define MROWS (BATCH * S_LEN)          // 8192
#define KVDIM (NKVH * HD_DIM)          // 512
#define QSCALE 0.08838834764831845f    // 1/sqrt(128)
#define PS_PITCH 68                    // shorts; 136B rows -> lg-groups at 0/32/64/96 mod 128

typedef __attribute__((ext_vector_type(8))) short bf16x8;
typedef __attribute__((ext_vector_type(4))) float f32x4;

#define BARRIER() asm volatile("s_barrier" ::: "memory")
#define WAITV(n)  asm volatile("s_waitcnt vmcnt(" #n ")" ::: "memory")

__device__ __forceinline__ unsigned short f2bf(float f) {
    unsigned int u = __float_as_uint(f);
    u += 0x7FFFu + ((u >> 16) & 1u);   // round-to-nearest-even
    return (unsigned short)(u >> 16);
}
__device__ __forceinline__ float bf2f(unsigned short h) {
    return __uint_as_float(((unsigned int)h) << 16);
}

// async global->LDS, 16B per lane; dest = uniform base + lane*16
__device__ __forceinline__ void gload_lds16(const void* g, void* lds) {
    __builtin_amdgcn_global_load_lds(
        (const __attribute__((address_space(1))) void*)g,
        (__attribute__((address_space(3))) void*)lds, 16, 0, 0);
}

// XOR swizzles (involutions on 16B slots), one per LDS row pitch.
__device__ __forceinline__ unsigned swz64 (unsigned off) { return off ^ (((off >> 7) & 3u) << 4); }
__device__ __forceinline__ unsigned swz128(unsigned off) { return off ^ (((off >> 7) & 7u) << 4); }
__device__ __forceinline__ unsigned swzK  (unsigned off) { return off ^ (((off >> 8) & 7u) << 4); }

// ---------------- cast x (fp32 -> bf16), vectorized ----------------
__global__ __launch_bounds__(256) void cast_f32_bf16(
    const float* __restrict__ in, unsigned short* __restrict__ out, int n4) {
    int i = blockIdx.x * blockDim.x + threadIdx.x;
    if (i >= n4) return;
    const float4 v = ((const float4*)in)[i];
    ushort4 o;
    o.x = f2bf(v.x); o.y = f2bf(v.y); o.z = f2bf(v.z); o.w = f2bf(v.w);
    ((ushort4*)out)[i] = o;
}

// ------------- transpose-cast weights: W[K][N] f32 -> Wt[N][K] bf16 -------------
__global__ __launch_bounds__(256) void transpose_cast(
    const float* __restrict__ W, unsigned short* __restrict__ Wt, int K, int N) {
    __shared__ float tile[64][65];
    const int bk = blockIdx.x, bn = blockIdx.y;
    const int t = threadIdx.x;
#pragma unroll
    for (int rep = 0; rep < 16; ++rep) {
        int idx = rep * 256 + t;
        int r = idx >> 6, c = idx & 63;
        tile[r][c] = W[(size_t)(bk * 64 + r) * N + bn * 64 + c];
    }
    __syncthreads();
#pragma unroll
    for (int rep = 0; rep < 16; ++rep) {
        int idx = rep * 256 + t;
        int r = idx >> 6, c = idx & 63;   // r = n-local, c = k-local
        Wt[(size_t)(bn * 64 + r) * K + bk * 64 + c] = f2bf(tile[c][r]);
    }
}

// ------------- RoPE in-place on bf16 [MROWS][nh*128]; scale folded in -------------
__global__ __launch_bounds__(256) void rope_kernel(
    unsigned short* __restrict__ q, const float* __restrict__ cosb,
    const float* __restrict__ sinb, int nh, float scale) {
    int gid = blockIdx.x * blockDim.x + threadIdx.x;
    int d = gid & 63;
    int h = (gid >> 6) % nh;
    int m = gid / (64 * nh);
    if (m >= MROWS) return;
    size_t base = (size_t)m * (nh * 128) + h * 128;
    float x1 = bf2f(q[base + d]);
    float x2 = bf2f(q[base + d + 64]);
    float c1 = cosb[m * 128 + d],  c2 = cosb[m * 128 + d + 64];
    float s1 = sinb[m * 128 + d],  s2 = sinb[m * 128 + d + 64];
    q[base + d]      = f2bf((x1 * c1 - x2 * s1) * scale);
    q[base + d + 64] = f2bf((x2 * c2 + x1 * s2) * scale);
}

// ------------- V transpose: vb[MROWS][512] -> vt[B][KVH][128][S] -------------
__global__ __launch_bounds__(256) void transpose_v(
    const unsigned short* __restrict__ V, unsigned short* __restrict__ Vt) {
    __shared__ unsigned short tile[64][65];
    const int st = blockIdx.x, dt = blockIdx.y, bk = blockIdx.z;
    const int b = bk / NKVH, kvh = bk % NKVH;
    const int t = threadIdx.x;
#pragma unroll
    for (int rep = 0; rep < 16; ++rep) {
        int idx = rep * 256 + t;
        int r = idx >> 6, c = idx & 63;  // r = s-local, c = d-local
        tile[r][c] = V[(size_t)(b * S_LEN + st * 64 + r) * KVDIM + kvh * HD_DIM + dt * 64 + c];
    }
    __syncthreads();
#pragma unroll
    for (int rep = 0; rep < 16; ++rep) {
        int idx = rep * 256 + t;
        int r = idx >> 6, c = idx & 63;  // r = d-local, c = s-local
        Vt[((size_t)(b * NKVH + kvh) * HD_DIM + dt * 64 + r) * S_LEN + st * 64 + c] = tile[c][r];
    }
}

// ------------- bf16 GEMM: C[M][N] = A[M][K] * Bt[N][K]^T -------------
// 128x128 tile, BK=32, 4 waves (2x2 of 64x64). XCD-swizzled block ids.
template <bool OUT_F32>
__global__ __launch_bounds__(256) void gemm_bt(
    const unsigned short* __restrict__ A, const unsigned short* __restrict__ Bt,
    void* __restrict__ Cout, int M, int N, int K) {
    __shared__ unsigned short As[128 * 32];
    __shared__ unsigned short Bs[128 * 32];
    const int nbn = N >> 7;
    int bid = blockIdx.x;
    const int cpx = gridDim.x >> 3;          // gridDim.x % 8 == 0 for all launches
    bid = (bid & 7) * cpx + (bid >> 3);      // bijective XCD chunking
    const int bm = bid / nbn, bn = bid % nbn;
    const int tid = threadIdx.x;
    const int w = tid >> 6, l = tid & 63;
    const int wm = w >> 1, wn = w & 1;
    const int lr = l & 15, lg = l >> 4;
    const unsigned m0 = bm << 7, n0 = bn << 7;

    f32x4 acc[4][4];
#pragma unroll
    for (int i = 0; i < 4; ++i)
#pragma unroll
        for (int j = 0; j < 4; ++j) acc[i][j] = (f32x4){0.f, 0.f, 0.f, 0.f};

    for (int k0 = 0; k0 < K; k0 += 32) {
        __syncthreads();
#pragma unroll
        for (int c = 0; c < 2; ++c) {
            unsigned ch = w * 2 + c;
            unsigned L = ch * 1024u + (unsigned)l * 16u;
            unsigned f = swz64(L);
            unsigned row = f >> 6, colb = f & 63u;
            const char* gA = (const char*)(A + (size_t)(m0 + row) * K + k0) + colb;
            gload_lds16(gA, (char*)As + ch * 1024u);
            const char* gB = (const char*)(Bt + (size_t)(n0 + row) * K + k0) + colb;
            gload_lds16(gB, (char*)Bs + ch * 1024u);
        }
        __syncthreads();
        bf16x8 af[4], bfr[4];
#pragma unroll
        for (int mf = 0; mf < 4; ++mf) {
            unsigned row = wm * 64 + mf * 16 + lr;
            af[mf] = *(const bf16x8*)((const char*)As + swz64(row * 64u + lg * 16u));
        }
#pragma unroll
        for (int nf = 0; nf < 4; ++nf) {
            unsigned row = wn * 64 + nf * 16 + lr;
            bfr[nf] = *(const bf16x8*)((const char*)Bs + swz64(row * 64u + lg * 16u));
        }
        __builtin_amdgcn_s_setprio(1);
#pragma unroll
        for (int mf = 0; mf < 4; ++mf)
#pragma unroll
            for (int nf = 0; nf < 4; ++nf)
                acc[mf][nf] = __builtin_amdgcn_mfma_f32_16x16x32_bf16(
                    af[mf], bfr[nf], acc[mf][nf], 0, 0, 0);
        __builtin_amdgcn_s_setprio(0);
    }
#pragma unroll
    for (int mf = 0; mf < 4; ++mf)
#pragma unroll
        for (int nf = 0; nf < 4; ++nf)
#pragma unroll
            for (int r = 0; r < 4; ++r) {
                unsigned row = m0 + wm * 64 + mf * 16 + lg * 4 + r;
                unsigned col = n0 + wn * 64 + nf * 16 + lr;
                float v = acc[mf][nf][r];
                if (OUT_F32) ((float*)Cout)[(size_t)row * N + col] = v;
                else ((unsigned short*)Cout)[(size_t)row * N + col] = f2bf(v);
            }
}

// ------------- causal GQA flash attention, KVBLK = 64, double-buffered -------------
// Block = 4 waves, 64 q-rows (16/wave). Q scale pre-folded into Qb.
// Pipeline: prefetch tile t+1 into buf^1 while computing tile t (counted vmcnt).
__global__ __launch_bounds__(256) void attn_fwd(
    const unsigned short* __restrict__ Qb, const unsigned short* __restrict__ Kb,
    const unsigned short* __restrict__ Vt, unsigned short* __restrict__ O) {
    __shared__ unsigned short Ks[2][64 * 128];    // 2 x 16 KB, 256B rows, swzK
    __shared__ unsigned short Vs[2][128 * 64];    // 2 x 16 KB, 128B rows, swz128
    __shared__ unsigned short Ps[4][16 * PS_PITCH];

    const int nqt = S_LEN / 64;                      // 64
    const int bh = blockIdx.x & (BATCH * NH - 1);    // 32 heads per q-tile
    const int qt = (nqt - 1) - (blockIdx.x >> 5);    // heavy tiles first
    const int b = bh >> 4, h = bh & 15;
    const int kvh = h >> 2;

    const int tid = threadIdx.x;
    const int w = tid >> 6, l = tid & 63;
    const int lr = l & 15, lg = l >> 4;
    const int sq_base = qt * 64 + w * 16;

    // Q fragments first (oldest vmem ops; drained by first counted wait)
    bf16x8 qf[4];
    {
        const unsigned short* qrow = Qb + (size_t)(b * S_LEN + sq_base + lr) * DMODEL + h * HD_DIM;
#pragma unroll
        for (int kk = 0; kk < 4; ++kk)
            qf[kk] = *(const bf16x8*)(qrow + kk * 32 + lg * 8);
    }

    const unsigned short* Kbase = Kb + (size_t)b * S_LEN * KVDIM + kvh * HD_DIM;
    const unsigned short* Vbase = Vt + (size_t)(b * NKVH + kvh) * HD_DIM * S_LEN;

    // stage one KV tile (8 gload_lds per wave)
    auto stage = [&](int t, int bufi) {
        const int kv0 = t * 64;
#pragma unroll
        for (int c = 0; c < 4; ++c) {
            unsigned ch = (unsigned)(w * 4 + c);
            unsigned L = ch * 1024u + (unsigned)l * 16u;
            unsigned fK = swzK(L);
            gload_lds16((const char*)(Kbase + (size_t)(kv0 + (fK >> 8)) * KVDIM) + (fK & 255u),
                        (char*)Ks[bufi] + ch * 1024u);
            unsigned fV = swz128(L);
            gload_lds16((const char*)(Vbase + (size_t)(fV >> 7) * S_LEN + kv0) + (fV & 127u),
                        (char*)Vs[bufi] + ch * 1024u);
        }
    };

    float mrun[4], lrun[4];
#pragma unroll
    for (int r = 0; r < 4; ++r) { mrun[r] = -INFINITY; lrun[r] = 0.f; }
    f32x4 acc[8];
#pragma unroll
    for (int d = 0; d < 8; ++d) acc[d] = (f32x4){0.f, 0.f, 0.f, 0.f};

    const int nt = qt + 1;
    stage(0, 0);

    for (int t = 0; t < nt; ++t) {
        const int bufi = t & 1;
        const int kv0 = t * 64;
        if (t + 1 < nt) {
            stage(t + 1, bufi ^ 1);
            WAITV(8);           // tile t's 8 loads done; t+1's 8 in flight
        } else {
            WAITV(0);
        }
        BARRIER();              // all waves' tile-t data resident

        const unsigned short* Kt = Ks[bufi];
        const unsigned short* Vtl = Vs[bufi];

        // ---- QK^T: S[16q][64kv] per wave ----
        f32x4 sc[4];
#pragma unroll
        for (int nf = 0; nf < 4; ++nf) sc[nf] = (f32x4){0.f, 0.f, 0.f, 0.f};
        __builtin_amdgcn_s_setprio(1);
#pragma unroll
        for (int kk = 0; kk < 4; ++kk)
#pragma unroll
            for (int nf = 0; nf < 4; ++nf) {
                unsigned row = nf * 16 + lr;
                bf16x8 kfr = *(const bf16x8*)((const char*)Kt + swzK(row * 256u + kk * 64u + lg * 16u));
                sc[nf] = __builtin_amdgcn_mfma_f32_16x16x32_bf16(qf[kk], kfr, sc[nf], 0, 0, 0);
            }
        __builtin_amdgcn_s_setprio(0);

        // ---- online softmax (rows r = lg*4+0..3 of this wave's 16) ----
#pragma unroll
        for (int r = 0; r < 4; ++r) {
            int q_abs = sq_base + lg * 4 + r;
            float s0 = sc[0][r]; if (kv0 + lr > q_abs)      s0 = -INFINITY;
            float s1 = sc[1][r]; if (kv0 + 16 + lr > q_abs) s1 = -INFINITY;
            float s2 = sc[2][r]; if (kv0 + 32 + lr > q_abs) s2 = -INFINITY;
            float s3 = sc[3][r]; if (kv0 + 48 + lr > q_abs) s3 = -INFINITY;
            float tm = fmaxf(fmaxf(s0, s1), fmaxf(s2, s3));
            tm = fmaxf(tm, __shfl_xor(tm, 1, 16));
            tm = fmaxf(tm, __shfl_xor(tm, 2, 16));
            tm = fmaxf(tm, __shfl_xor(tm, 4, 16));
            tm = fmaxf(tm, __shfl_xor(tm, 8, 16));
            float mnew = fmaxf(mrun[r], tm);
            float corr = __expf(mrun[r] - mnew);
            float p0 = __expf(s0 - mnew);
            float p1 = __expf(s1 - mnew);
            float p2 = __expf(s2 - mnew);
            float p3 = __expf(s3 - mnew);
            float rs = (p0 + p1) + (p2 + p3);
            rs += __shfl_xor(rs, 1, 16);
            rs += __shfl_xor(rs, 2, 16);
            rs += __shfl_xor(rs, 4, 16);
            rs += __shfl_xor(rs, 8, 16);
            lrun[r] = corr * lrun[r] + rs;
            mrun[r] = mnew;
#pragma unroll
            for (int d = 0; d < 8; ++d) acc[d][r] *= corr;
            int prow = (lg * 4 + r) * PS_PITCH;
            Ps[w][prow + lr]      = f2bf(p0);
            Ps[w][prow + 16 + lr] = f2bf(p1);
            Ps[w][prow + 32 + lr] = f2bf(p2);
            Ps[w][prow + 48 + lr] = f2bf(p3);
        }

        // ---- PV: O[16q][128d] += P[16q][64kv] * V[64kv][128d] ----
        bf16x8 pf[2];
#pragma unroll
        for (int ks = 0; ks < 2; ++ks)
            pf[ks] = *(const bf16x8*)(&Ps[w][lr * PS_PITCH + ks * 32 + lg * 8]);
        __builtin_amdgcn_s_setprio(1);
#pragma unroll
        for (int d = 0; d < 8; ++d)
#pragma unroll
            for (int ks = 0; ks < 2; ++ks) {
                unsigned row = d * 16 + lr;
                bf16x8 vf = *(const bf16x8*)((const char*)Vtl + swz128(row * 128u + ks * 64u + lg * 16u));
                acc[d] = __builtin_amdgcn_mfma_f32_16x16x32_bf16(pf[ks], vf, acc[d], 0, 0, 0);
            }
        __builtin_amdgcn_s_setprio(0);

        BARRIER();              // all waves done reading buf[t&1]
    }

    float inv[4];
#pragma unroll
    for (int r = 0; r < 4; ++r) inv[r] = 1.f / lrun[r];
#pragma unroll
    for (int d = 0; d < 8; ++d)
#pragma unroll
        for (int r = 0; r < 4; ++r) {
            size_t row = (size_t)(b * S_LEN + sq_base + lg * 4 + r);
            O[row * DMODEL + h * HD_DIM + d * 16 + lr] = f2bf(acc[d][r] * inv[r]);
        }
}

extern "C" void kernel_launch(void* const* d_in, const int* in_sizes, int n_in,
                              void* d_out, int out_size, void* d_ws, size_t ws_size,
                              hipStream_t stream) {
    (void)in_sizes; (void)n_in; (void)out_size; (void)ws_size;
    const float* x    = (const float*)d_in[0];
    const float* cosb = (const float*)d_in[1];
    const float* sinb = (const float*)d_in[2];
    const float* wq   = (const float*)d_in[3];
    const float* wk   = (const float*)d_in[4];
    const float* wv   = (const float*)d_in[5];
    const float* wo   = (const float*)d_in[6];
    float* out = (float*)d_out;

    char* ws = (char*)d_ws;
    const size_t MB = 1ull << 20;
    unsigned short* xb  = (unsigned short*)(ws + 0);        // 32MB (x bf16; dead after V GEMM)
    unsigned short* aob = (unsigned short*)(ws + 0);        // 32MB (attn out; reuses xb)
    unsigned short* wqt = (unsigned short*)(ws + 32 * MB);  // 8MB
    unsigned short* wkt = (unsigned short*)(ws + 40 * MB);  // 2MB
    unsigned short* wvt = (unsigned short*)(ws + 42 * MB);  // 2MB
    unsigned short* wot = (unsigned short*)(ws + 44 * MB);  // 8MB
    unsigned short* qb  = (unsigned short*)(ws + 52 * MB);  // 32MB
    unsigned short* kb  = (unsigned short*)(ws + 84 * MB);  // 8MB
    unsigned short* vb  = (unsigned short*)(ws + 92 * MB);  // 8MB
    unsigned short* vtb = (unsigned short*)(ws + 100 * MB); // 8MB  (total 108MB)

    cast_f32_bf16<<<16384, 256, 0, stream>>>(x, xb, (MROWS * DMODEL) / 4);
    transpose_cast<<<dim3(32, 32), 256, 0, stream>>>(wq, wqt, DMODEL, DMODEL);
    transpose_cast<<<dim3(32, 8),  256, 0, stream>>>(wk, wkt, DMODEL, KVDIM);
    transpose_cast<<<dim3(32, 8),  256, 0, stream>>>(wv, wvt, DMODEL, KVDIM);
    transpose_cast<<<dim3(32, 32), 256, 0, stream>>>(wo, wot, DMODEL, DMODEL);

    gemm_bt<false><<<1024, 256, 0, stream>>>(xb, wqt, qb, MROWS, DMODEL, DMODEL);
    gemm_bt<false><<<256,  256, 0, stream>>>(xb, wkt, kb, MROWS, KVDIM, DMODEL);
    gemm_bt<false><<<256,  256, 0, stream>>>(xb, wvt, vb, MROWS, KVDIM, DMODEL);

    rope_kernel<<<(MROWS * NH * 64) / 256,   256, 0, stream>>>(qb, cosb, sinb, NH, QSCALE);
    rope_kernel<<<(MROWS * NKVH * 64) / 256, 256, 0, stream>>>(kb, cosb, sinb, NKVH, 1.0f);
    transpose_v<<<dim3(64, 2, 8), 256, 0, stream>>>(vb, vtb);

    attn_fwd<<<2048, 256, 0, stream>>>(qb, kb, vtb, aob);

    gemm_bt<true><<<1024, 256, 0, stream>>>(aob, wot, out, MROWS, DMODEL, DMODEL);
}

// Round 4
// 631.819 us; speedup vs baseline: 1.3205x; 1.2638x over previous
//
#include <hip/hip_runtime.h>

// Problem constants (B=2, S=4096, D=2048, H=16, KVH=4, HD=128)
#define S_LEN 4096
#define BATCH 2
#define NH 16
#define NKVH 4
#define HD_DIM 128
#define DMODEL 2048
#define MROWS (BATCH * S_LEN)          // 8192
#define KVDIM (NKVH * HD_DIM)          // 512
#define QSCALE 0.08838834764831845f    // 1/sqrt(128)

typedef __attribute__((ext_vector_type(8))) short bf16x8;
typedef __attribute__((ext_vector_type(4))) float f32x4;
typedef __attribute__((ext_vector_type(16))) float f32x16;
typedef __attribute__((ext_vector_type(4))) int i32x4;
typedef __attribute__((ext_vector_type(2))) int i32x2;

#define BARRIER() asm volatile("s_barrier" ::: "memory")
#define WAITV(n)  asm volatile("s_waitcnt vmcnt(" #n ")" ::: "memory")

__device__ __forceinline__ unsigned short f2bf(float f) {
    unsigned int u = __float_as_uint(f);
    u += 0x7FFFu + ((u >> 16) & 1u);   // round-to-nearest-even
    return (unsigned short)(u >> 16);
}
__device__ __forceinline__ float bf2f(unsigned short h) {
    return __uint_as_float(((unsigned int)h) << 16);
}

// v_cvt_pk_bf16_f32: lo -> low half, hi -> high half
__device__ __forceinline__ int cvtpk(float lo, float hi) {
    int r;
    asm("v_cvt_pk_bf16_f32 %0, %1, %2" : "=v"(r) : "v"(lo), "v"(hi));
    return r;
}

// permlane32_swap: a'[i<32]=a[i], a'[i>=32]=b[i-32]; b'[i<32]=a[i+32], b'[i>=32]=b[i]
__device__ __forceinline__ void swap32(int& a, int& b) {
#if __has_builtin(__builtin_amdgcn_permlane32_swap)
    i32x2 r = __builtin_amdgcn_permlane32_swap(a, b, false, false);
    a = r.x; b = r.y;
#else
    int pa = __shfl_xor(b, 32, 64);
    int pb = __shfl_xor(a, 32, 64);
    int lane = threadIdx.x & 63;
    int na = (lane < 32) ? a : pa;
    int nb = (lane < 32) ? pb : b;
    a = na; b = nb;
#endif
}

// value held by lane^32 (both halves compute symmetric reductions)
__device__ __forceinline__ float partner32(float x) {
#if __has_builtin(__builtin_amdgcn_permlane32_swap)
    int xi = __float_as_int(x);
    i32x2 r = __builtin_amdgcn_permlane32_swap(xi, xi, false, false);
    return __int_as_float(((threadIdx.x & 32) ? r.x : r.y));
#else
    return __shfl_xor(x, 32, 64);
#endif
}

// async global->LDS, 16B per lane; dest = uniform base + lane*16
__device__ __forceinline__ void gload_lds16(const void* g, void* lds) {
    __builtin_amdgcn_global_load_lds(
        (const __attribute__((address_space(1))) void*)g,
        (__attribute__((address_space(3))) void*)lds, 16, 0, 0);
}

// XOR swizzles (involutions on 16B slots), one per LDS row pitch.
__device__ __forceinline__ unsigned swz64 (unsigned off) { return off ^ (((off >> 7) & 3u) << 4); }
__device__ __forceinline__ unsigned swz128(unsigned off) { return off ^ (((off >> 7) & 7u) << 4); }
__device__ __forceinline__ unsigned swzK  (unsigned off) { return off ^ (((off >> 8) & 7u) << 4); }

// ---------------- cast x (fp32 -> bf16), vectorized ----------------
__global__ __launch_bounds__(256) void cast_f32_bf16(
    const float* __restrict__ in, unsigned short* __restrict__ out, int n4) {
    int i = blockIdx.x * blockDim.x + threadIdx.x;
    if (i >= n4) return;
    const float4 v = ((const float4*)in)[i];
    ushort4 o;
    o.x = f2bf(v.x); o.y = f2bf(v.y); o.z = f2bf(v.z); o.w = f2bf(v.w);
    ((ushort4*)out)[i] = o;
}

// ------------- transpose-cast weights: W[K][N] f32 -> Wt[N][K] bf16 -------------
__global__ __launch_bounds__(256) void transpose_cast(
    const float* __restrict__ W, unsigned short* __restrict__ Wt, int K, int N) {
    __shared__ float tile[64][65];
    const int bk = blockIdx.x, bn = blockIdx.y;
    const int t = threadIdx.x;
#pragma unroll
    for (int rep = 0; rep < 16; ++rep) {
        int idx = rep * 256 + t;
        int r = idx >> 6, c = idx & 63;
        tile[r][c] = W[(size_t)(bk * 64 + r) * N + bn * 64 + c];
    }
    __syncthreads();
#pragma unroll
    for (int rep = 0; rep < 16; ++rep) {
        int idx = rep * 256 + t;
        int r = idx >> 6, c = idx & 63;   // r = n-local, c = k-local
        Wt[(size_t)(bn * 64 + r) * K + bk * 64 + c] = f2bf(tile[c][r]);
    }
}

// ------------- RoPE in-place on bf16 [MROWS][nh*128]; scale folded in -------------
__global__ __launch_bounds__(256) void rope_kernel(
    unsigned short* __restrict__ q, const float* __restrict__ cosb,
    const float* __restrict__ sinb, int nh, float scale) {
    int gid = blockIdx.x * blockDim.x + threadIdx.x;
    int d = gid & 63;
    int h = (gid >> 6) % nh;
    int m = gid / (64 * nh);
    if (m >= MROWS) return;
    size_t base = (size_t)m * (nh * 128) + h * 128;
    float x1 = bf2f(q[base + d]);
    float x2 = bf2f(q[base + d + 64]);
    float c1 = cosb[m * 128 + d],  c2 = cosb[m * 128 + d + 64];
    float s1 = sinb[m * 128 + d],  s2 = sinb[m * 128 + d + 64];
    q[base + d]      = f2bf((x1 * c1 - x2 * s1) * scale);
    q[base + d + 64] = f2bf((x2 * c2 + x1 * s2) * scale);
}

// ------------- V transpose: vb[MROWS][512] -> vt[B][KVH][128][S] -------------
__global__ __launch_bounds__(256) void transpose_v(
    const unsigned short* __restrict__ V, unsigned short* __restrict__ Vt) {
    __shared__ unsigned short tile[64][65];
    const int st = blockIdx.x, dt = blockIdx.y, bk = blockIdx.z;
    const int b = bk / NKVH, kvh = bk % NKVH;
    const int t = threadIdx.x;
#pragma unroll
    for (int rep = 0; rep < 16; ++rep) {
        int idx = rep * 256 + t;
        int r = idx >> 6, c = idx & 63;  // r = s-local, c = d-local
        tile[r][c] = V[(size_t)(b * S_LEN + st * 64 + r) * KVDIM + kvh * HD_DIM + dt * 64 + c];
    }
    __syncthreads();
#pragma unroll
    for (int rep = 0; rep < 16; ++rep) {
        int idx = rep * 256 + t;
        int r = idx >> 6, c = idx & 63;  // r = d-local, c = s-local
        Vt[((size_t)(b * NKVH + kvh) * HD_DIM + dt * 64 + r) * S_LEN + st * 64 + c] = tile[c][r];
    }
}

// ------------- bf16 GEMM: C[M][N] = A[M][K] * Bt[N][K]^T -------------
template <bool OUT_F32>
__global__ __launch_bounds__(256) void gemm_bt(
    const unsigned short* __restrict__ A, const unsigned short* __restrict__ Bt,
    void* __restrict__ Cout, int M, int N, int K) {
    __shared__ unsigned short As[128 * 32];
    __shared__ unsigned short Bs[128 * 32];
    const int nbn = N >> 7;
    int bid = blockIdx.x;
    const int cpx = gridDim.x >> 3;          // gridDim.x % 8 == 0 for all launches
    bid = (bid & 7) * cpx + (bid >> 3);      // bijective XCD chunking
    const int bm = bid / nbn, bn = bid % nbn;
    const int tid = threadIdx.x;
    const int w = tid >> 6, l = tid & 63;
    const int wm = w >> 1, wn = w & 1;
    const int lr = l & 15, lg = l >> 4;
    const unsigned m0 = bm << 7, n0 = bn << 7;

    f32x4 acc[4][4];
#pragma unroll
    for (int i = 0; i < 4; ++i)
#pragma unroll
        for (int j = 0; j < 4; ++j) acc[i][j] = (f32x4){0.f, 0.f, 0.f, 0.f};

    for (int k0 = 0; k0 < K; k0 += 32) {
        __syncthreads();
#pragma unroll
        for (int c = 0; c < 2; ++c) {
            unsigned ch = w * 2 + c;
            unsigned L = ch * 1024u + (unsigned)l * 16u;
            unsigned f = swz64(L);
            unsigned row = f >> 6, colb = f & 63u;
            const char* gA = (const char*)(A + (size_t)(m0 + row) * K + k0) + colb;
            gload_lds16(gA, (char*)As + ch * 1024u);
            const char* gB = (const char*)(Bt + (size_t)(n0 + row) * K + k0) + colb;
            gload_lds16(gB, (char*)Bs + ch * 1024u);
        }
        __syncthreads();
        bf16x8 af[4], bfr[4];
#pragma unroll
        for (int mf = 0; mf < 4; ++mf) {
            unsigned row = wm * 64 + mf * 16 + lr;
            af[mf] = *(const bf16x8*)((const char*)As + swz64(row * 64u + lg * 16u));
        }
#pragma unroll
        for (int nf = 0; nf < 4; ++nf) {
            unsigned row = wn * 64 + nf * 16 + lr;
            bfr[nf] = *(const bf16x8*)((const char*)Bs + swz64(row * 64u + lg * 16u));
        }
        __builtin_amdgcn_s_setprio(1);
#pragma unroll
        for (int mf = 0; mf < 4; ++mf)
#pragma unroll
            for (int nf = 0; nf < 4; ++nf)
                acc[mf][nf] = __builtin_amdgcn_mfma_f32_16x16x32_bf16(
                    af[mf], bfr[nf], acc[mf][nf], 0, 0, 0);
        __builtin_amdgcn_s_setprio(0);
    }
#pragma unroll
    for (int mf = 0; mf < 4; ++mf)
#pragma unroll
        for (int nf = 0; nf < 4; ++nf)
#pragma unroll
            for (int r = 0; r < 4; ++r) {
                unsigned row = m0 + wm * 64 + mf * 16 + lg * 4 + r;
                unsigned col = n0 + wn * 64 + nf * 16 + lr;
                float v = acc[mf][nf][r];
                if (OUT_F32) ((float*)Cout)[(size_t)row * N + col] = v;
                else ((unsigned short*)Cout)[(size_t)row * N + col] = f2bf(v);
            }
}

// ------------- causal GQA flash attention: swapped-QK^T 32x32, in-register softmax -------------
// Block = 4 waves x 32 q-rows = 128 q. KVBLK=64, double-buffered LDS, counted vmcnt.
// Each lane owns ONE q-row: S^T = mfma(K, Q) -> 32 scores/lane (+partner lane has other 32? no:
// lane l and l^32 hold complementary kv-subsets of the SAME q; reduce via permlane32_swap).
// P -> PV B-fragment via cvt_pk_bf16 + permlane32_swap (T12). Defer-max rescale (T13, THR=8).
__global__ __launch_bounds__(256, 2) void attn_fwd(
    const unsigned short* __restrict__ Qb, const unsigned short* __restrict__ Kb,
    const unsigned short* __restrict__ Vt, unsigned short* __restrict__ O) {
    __shared__ __align__(16) unsigned short Ks[2][64 * 128];   // 2 x 16KB, 256B rows, swzK
    __shared__ __align__(16) unsigned short Vs[2][128 * 64];   // 2 x 16KB, 128B rows, swz128

    const int bh = blockIdx.x & 31;            // 32 (b,h) combos
    const int qt = 31 - (blockIdx.x >> 5);     // heavy q-tiles first
    const int b = bh >> 4, h = bh & 15;
    const int kvh = h >> 2;

    const int tid = threadIdx.x;
    const int w = tid >> 6, l = tid & 63;
    const int lq = l & 31;
    const int hi = l >> 5;                     // which k-half of fragments this lane holds
    const int hi16 = hi << 4;                  // byte offset of k-slice in frag reads
    const int hi4 = hi << 2;                   // kv/d offset in C/D layout
    const int q0w = qt * 128 + w * 32;
    const int q_abs = q0w + lq;

    // Q fragments (B-operand): lane needs Q[q_abs][dstep*16 + hi*8 + 0..7]
    bf16x8 qf[8];
    {
        const unsigned short* qrow = Qb + (size_t)(b * S_LEN + q_abs) * DMODEL + h * HD_DIM;
#pragma unroll
        for (int ds_ = 0; ds_ < 8; ++ds_)
            qf[ds_] = *(const bf16x8*)(qrow + ds_ * 16 + hi * 8);
    }

    const unsigned short* Kbase = Kb + (size_t)b * S_LEN * KVDIM + kvh * HD_DIM;
    const unsigned short* Vbase = Vt + (size_t)(b * NKVH + kvh) * HD_DIM * S_LEN;

    auto stage = [&](int t, int bufi) {
        const int kv0 = t * 64;
#pragma unroll
        for (int c = 0; c < 4; ++c) {
            unsigned ch = (unsigned)(w * 4 + c);
            unsigned L = ch * 1024u + (unsigned)l * 16u;
            unsigned fK = swzK(L);
            gload_lds16((const char*)(Kbase + (size_t)(kv0 + (fK >> 8)) * KVDIM) + (fK & 255u),
                        (char*)Ks[bufi] + ch * 1024u);
            unsigned fV = swz128(L);
            gload_lds16((const char*)(Vbase + (size_t)(fV >> 7) * S_LEN + kv0) + (fV & 127u),
                        (char*)Vs[bufi] + ch * 1024u);
        }
    };

    float mrun = -__builtin_inff(), lrun = 0.f;
    f32x16 acc[4];
#pragma unroll
    for (int d_ = 0; d_ < 4; ++d_)
#pragma unroll
        for (int r = 0; r < 16; ++r) acc[d_][r] = 0.f;

    const unsigned kxv = (unsigned)((lq & 7) << 4);     // swizzle XOR (row&7 = lq&7)
    const unsigned kb0 = (unsigned)lq * 256u + (unsigned)hi16;   // K frag base (kvsub 0)
    const unsigned vb0 = (unsigned)lq * 128u + (unsigned)hi16;   // V frag base (dsub 0)

    const int nt = 2 * qt + 2;
    stage(0, 0);

    for (int t = 0; t < nt; ++t) {
        const int bufi = t & 1;
        const int kv0 = t * 64;
        if (t + 1 < nt) {
            stage(t + 1, bufi ^ 1);
            WAITV(8);           // tile t's 8 loads done; t+1's in flight
        } else {
            WAITV(0);
        }
        BARRIER();

        if (kv0 <= q0w + 31) {  // wave-uniform causal skip
            const char* Kt  = (const char*)Ks[bufi];
            const char* Vtl = (const char*)Vs[bufi];

            // ---- S^T[64kv][32q]: two 32x32 MFMAs chains over d ----
            f32x16 st0, st1;
#pragma unroll
            for (int r = 0; r < 16; ++r) { st0[r] = 0.f; st1[r] = 0.f; }
            __builtin_amdgcn_s_setprio(1);
#pragma unroll
            for (int ds_ = 0; ds_ < 8; ++ds_) {
                bf16x8 k0 = *(const bf16x8*)(Kt + ((kb0 + ds_ * 32u) ^ kxv));
                st0 = __builtin_amdgcn_mfma_f32_32x32x16_bf16(k0, qf[ds_], st0, 0, 0, 0);
                bf16x8 k1 = *(const bf16x8*)(Kt + ((kb0 + 8192u + ds_ * 32u) ^ kxv));
                st1 = __builtin_amdgcn_mfma_f32_32x32x16_bf16(k1, qf[ds_], st1, 0, 0, 0);
            }
            __builtin_amdgcn_s_setprio(0);

            // ---- causal mask (only the wave's single diagonal-straddling tile) ----
            if (kv0 + 63 > q0w) {
                const int limm = q_abs - kv0 - hi4;   // kvrel > limm -> masked
#pragma unroll
                for (int r = 0; r < 16; ++r) {
                    const int kvrel = (r & 3) + 8 * (r >> 2);
                    if (kvrel > limm)      st0[r] = -__builtin_inff();
                    if (kvrel + 32 > limm) st1[r] = -__builtin_inff();
                }
            }

            // ---- in-lane softmax over 32 values (+partner for the other 32) ----
            float v[32];
#pragma unroll
            for (int r = 0; r < 16; ++r) { v[r] = st0[r]; v[16 + r] = st1[r]; }
#pragma unroll
            for (int s2 = 16; s2 >= 1; s2 >>= 1)
#pragma unroll
                for (int i = 0; i < 16; ++i) if (i < s2) v[i] = fmaxf(v[i], v[i + s2]);
            float pm = fmaxf(v[0], partner32(v[0]));

            const float mnew = fmaxf(mrun, pm);
            if (!__all(pm - mrun <= 8.f)) {           // T13 defer-max
                const float corr = __expf(mrun - mnew);
                mrun = mnew;
                lrun *= corr;
#pragma unroll
                for (int d_ = 0; d_ < 4; ++d_)
#pragma unroll
                    for (int r = 0; r < 16; ++r) acc[d_][r] *= corr;
            }

#pragma unroll
            for (int r = 0; r < 16; ++r) {
                st0[r] = __expf(st0[r] - mrun);
                st1[r] = __expf(st1[r] - mrun);
            }
            float s[32];
#pragma unroll
            for (int r = 0; r < 16; ++r) { s[r] = st0[r]; s[16 + r] = st1[r]; }
#pragma unroll
            for (int s2 = 16; s2 >= 1; s2 >>= 1)
#pragma unroll
                for (int i = 0; i < 16; ++i) if (i < s2) s[i] += s[i + s2];
            lrun += s[0] + partner32(s[0]);

            // ---- PV: O^T[128d][32q] += V^T[d][kv] * P^T[kv][q] ----
            __builtin_amdgcn_s_setprio(1);
#pragma unroll
            for (int kb = 0; kb < 4; ++kb) {
                const int rb = (kb & 1) * 8;
                float e0, e1, e2, e3, e4, e5, e6, e7;
                if (kb < 2) {
                    e0 = st0[rb + 0]; e1 = st0[rb + 1]; e2 = st0[rb + 2]; e3 = st0[rb + 3];
                    e4 = st0[rb + 4]; e5 = st0[rb + 5]; e6 = st0[rb + 6]; e7 = st0[rb + 7];
                } else {
                    e0 = st1[rb + 0]; e1 = st1[rb + 1]; e2 = st1[rb + 2]; e3 = st1[rb + 3];
                    e4 = st1[rb + 4]; e5 = st1[rb + 5]; e6 = st1[rb + 6]; e7 = st1[rb + 7];
                }
                int a0 = cvtpk(e0, e1), a1 = cvtpk(e2, e3);
                int b0 = cvtpk(e4, e5), b1 = cvtpk(e6, e7);
                swap32(a0, b0);    // -> frag words 0 and 2
                swap32(a1, b1);    // -> frag words 1 and 3
                i32x4 wv = {a0, a1, b0, b1};
                bf16x8 pf = __builtin_bit_cast(bf16x8, wv);
#pragma unroll
                for (int dsub = 0; dsub < 4; ++dsub) {
                    bf16x8 vf = *(const bf16x8*)(Vtl + ((vb0 + dsub * 4096u + kb * 32u) ^ kxv));
                    acc[dsub] = __builtin_amdgcn_mfma_f32_32x32x16_bf16(vf, pf, acc[dsub], 0, 0, 0);
                }
            }
            __builtin_amdgcn_s_setprio(0);
        }

        BARRIER();
    }

    // ---- epilogue: O[q][d] = acc^T / l ----
    const float inv = 1.f / lrun;
    unsigned short* orow = O + (size_t)(b * S_LEN + q_abs) * DMODEL + h * HD_DIM;
#pragma unroll
    for (int dsub = 0; dsub < 4; ++dsub)
#pragma unroll
        for (int g = 0; g < 4; ++g) {
            ushort4 o;
            o.x = f2bf(acc[dsub][g * 4 + 0] * inv);
            o.y = f2bf(acc[dsub][g * 4 + 1] * inv);
            o.z = f2bf(acc[dsub][g * 4 + 2] * inv);
            o.w = f2bf(acc[dsub][g * 4 + 3] * inv);
            *(ushort4*)(orow + dsub * 32 + g * 8 + hi4) = o;
        }
}

extern "C" void kernel_launch(void* const* d_in, const int* in_sizes, int n_in,
                              void* d_out, int out_size, void* d_ws, size_t ws_size,
                              hipStream_t stream) {
    (void)in_sizes; (void)n_in; (void)out_size; (void)ws_size;
    const float* x    = (const float*)d_in[0];
    const float* cosb = (const float*)d_in[1];
    const float* sinb = (const float*)d_in[2];
    const float* wq   = (const float*)d_in[3];
    const float* wk   = (const float*)d_in[4];
    const float* wv   = (const float*)d_in[5];
    const float* wo   = (const float*)d_in[6];
    float* out = (float*)d_out;

    char* ws = (char*)d_ws;
    const size_t MB = 1ull << 20;
    unsigned short* xb  = (unsigned short*)(ws + 0);        // 32MB (x bf16; dead after V GEMM)
    unsigned short* aob = (unsigned short*)(ws + 0);        // 32MB (attn out; reuses xb)
    unsigned short* wqt = (unsigned short*)(ws + 32 * MB);  // 8MB
    unsigned short* wkt = (unsigned short*)(ws + 40 * MB);  // 2MB
    unsigned short* wvt = (unsigned short*)(ws + 42 * MB);  // 2MB
    unsigned short* wot = (unsigned short*)(ws + 44 * MB);  // 8MB
    unsigned short* qb  = (unsigned short*)(ws + 52 * MB);  // 32MB
    unsigned short* kb  = (unsigned short*)(ws + 84 * MB);  // 8MB
    unsigned short* vb  = (unsigned short*)(ws + 92 * MB);  // 8MB
    unsigned short* vtb = (unsigned short*)(ws + 100 * MB); // 8MB  (total 108MB)

    cast_f32_bf16<<<16384, 256, 0, stream>>>(x, xb, (MROWS * DMODEL) / 4);
    transpose_cast<<<dim3(32, 32), 256, 0, stream>>>(wq, wqt, DMODEL, DMODEL);
    transpose_cast<<<dim3(32, 8),  256, 0, stream>>>(wk, wkt, DMODEL, KVDIM);
    transpose_cast<<<dim3(32, 8),  256, 0, stream>>>(wv, wvt, DMODEL, KVDIM);
    transpose_cast<<<dim3(32, 32), 256, 0, stream>>>(wo, wot, DMODEL, DMODEL);

    gemm_bt<false><<<1024, 256, 0, stream>>>(xb, wqt, qb, MROWS, DMODEL, DMODEL);
    gemm_bt<false><<<256,  256, 0, stream>>>(xb, wkt, kb, MROWS, KVDIM, DMODEL);
    gemm_bt<false><<<256,  256, 0, stream>>>(xb, wvt, vb, MROWS, KVDIM, DMODEL);

    rope_kernel<<<(MROWS * NH * 64) / 256,   256, 0, stream>>>(qb, cosb, sinb, NH, QSCALE);
    rope_kernel<<<(MROWS * NKVH * 64) / 256, 256, 0, stream>>>(kb, cosb, sinb, NKVH, 1.0f);
    transpose_v<<<dim3(64, 2, 8), 256, 0, stream>>>(vb, vtb);

    attn_fwd<<<1024, 256, 0, stream>>>(qb, kb, vtb, aob);

    gemm_bt<true><<<1024, 256, 0, stream>>>(aob, wot, out, MROWS, DMODEL, DMODEL);
}